// Round 18
// baseline (851.311 us; speedup 1.0000x reference)
//
#include <hip/hip_runtime.h>
#include <hip/hip_bf16.h>
#include <math.h>
#include <string.h>

#define DEV __device__ __forceinline__

typedef __bf16 bf16;
typedef bf16 bf16x8 __attribute__((ext_vector_type(8)));
typedef bf16 bf16x2 __attribute__((ext_vector_type(2)));
typedef float f32x4 __attribute__((ext_vector_type(4)));
typedef float f32x2 __attribute__((ext_vector_type(2)));
typedef unsigned int uint;
typedef uint u32x4 __attribute__((ext_vector_type(4)));
typedef unsigned char uchar;
typedef unsigned short ushort;

constexpr int N_NODES = 50000;
constexpr int N_EDGES = 800000;
constexpr int H = 128;
constexpr int NB_SCAN = (N_NODES + 255) / 256;  // 196

DEV float fsilu(float x) { return x / (1.f + __expf(-x)); }
DEV float fsigmoid(float x) { return 1.f / (1.f + __expf(-x)); }

// ---------------- small prep kernels ----------------

__global__ void transpose_pad_kernel(bf16* __restrict__ dst, const float* __restrict__ src,
                                     int K, int Nf, int KP) {
    int idx = blockIdx.x * 256 + threadIdx.x;
    if (idx >= Nf * KP) return;
    int n = idx / KP, k = idx - n * KP;
    dst[idx] = (k < K) ? (bf16)src[k * Nf + n] : (bf16)0.f;
}

__global__ void h_init_kernel(const float* __restrict__ h, float* __restrict__ h_cur, int n) {
    int i = blockIdx.x * 256 + threadIdx.x;
    if (i < n) h_cur[i] = h[i];
}

__global__ void out_h_kernel(const float* __restrict__ h_cur, const float* __restrict__ nmask,
                             float* __restrict__ out) {
    int i = blockIdx.x * 256 + threadIdx.x;
    if (i < N_NODES * H) out[i] = h_cur[i] * nmask[i >> 7];
}

// ---------------- CSR build (group edges by row) ----------------

__global__ void count_kernel(const int* __restrict__ ei, int* __restrict__ deg) {
    int e = blockIdx.x * 256 + threadIdx.x;
    if (e < N_EDGES) atomicAdd(&deg[ei[e]], 1);
}

__global__ void scan1_kernel(const int* __restrict__ deg, int* __restrict__ off,
                             int* __restrict__ bsum) {
    __shared__ int s[256];
    int t = threadIdx.x, i = blockIdx.x * 256 + t;
    int v = (i < N_NODES) ? deg[i] : 0;
    s[t] = v;
    __syncthreads();
#pragma unroll
    for (int st = 1; st < 256; st <<= 1) {
        int x = (t >= st) ? s[t - st] : 0;
        __syncthreads();
        s[t] += x;
        __syncthreads();
    }
    if (i < N_NODES) off[i] = s[t] - v;
    if (t == 255) bsum[blockIdx.x] = s[255];
}

__global__ void scan2_kernel(int* __restrict__ bsum) {
    __shared__ int s[256];
    int t = threadIdx.x;
    int v = (t < NB_SCAN) ? bsum[t] : 0;
    s[t] = v;
    __syncthreads();
#pragma unroll
    for (int st = 1; st < 256; st <<= 1) {
        int x = (t >= st) ? s[t - st] : 0;
        __syncthreads();
        s[t] += x;
        __syncthreads();
    }
    if (t < NB_SCAN) bsum[t] = s[t] - v;
}

__global__ void scan3_kernel(int* __restrict__ off, const int* __restrict__ bsum) {
    int i = blockIdx.x * 256 + threadIdx.x;
    if (i >= N_NODES) return;
    off[i] += bsum[blockIdx.x];
}

__global__ void fill2_kernel(const int* __restrict__ ei, const float* __restrict__ eattr,
                             const float* __restrict__ emask, int* __restrict__ off,
                             uint* __restrict__ rc_pm, bf16* __restrict__ eaem_pm) {
    int e = blockIdx.x * 256 + threadIdx.x;
    if (e >= N_EDGES) return;
    int r = ei[e], c = ei[N_EDGES + e];
    int slot = atomicAdd(&off[r], 1);
    rc_pm[slot] = ((uint)r << 16) | (uint)c;
    eaem_pm[(size_t)slot * 2 + 0] = (bf16)eattr[e];
    eaem_pm[(size_t)slot * 2 + 1] = (bf16)emask[e];
}

// ---------------- per-node P/Q precompute ----------------
__global__ __launch_bounds__(256, 2) void pq_kernel(
    const float* __restrict__ h_cur, const bf16* __restrict__ w1t,
    const float* __restrict__ b1, bf16* __restrict__ P, bf16* __restrict__ Q) {
    __shared__ __align__(16) bf16 hs[64 * 128];
    int t = threadIdx.x, lane = t & 63, wv = t >> 6;
    int lr = lane & 15, lg = lane >> 4;
    int nbase = blockIdx.x * 64;

    {   // stage bf16(h) swizzled
        int nl = t >> 2, q = t & 3;
        int node = nbase + nl;
        if (node < N_NODES) {
            const float4* hr = (const float4*)(h_cur + (size_t)node * H);
#pragma unroll
            for (int c = 0; c < 4; ++c) {
                float4 v0 = hr[q * 8 + c * 2];
                float4 v1 = hr[q * 8 + c * 2 + 1];
                bf16x8 o;
                o[0] = (bf16)v0.x; o[1] = (bf16)v0.y; o[2] = (bf16)v0.z; o[3] = (bf16)v0.w;
                o[4] = (bf16)v1.x; o[5] = (bf16)v1.y; o[6] = (bf16)v1.z; o[7] = (bf16)v1.w;
                int sl = (q * 4 + c) ^ (nl & 7);
                *(bf16x8*)(hs + nl * 128 + sl * 8) = o;
            }
        } else {
#pragma unroll
            for (int c = 0; c < 4; ++c) {
                int sl = (q * 4 + c) ^ (nl & 7);
                *(bf16x8*)(hs + nl * 128 + sl * 8) = (bf16x8)(bf16)0.f;
            }
        }
    }
    __syncthreads();

    f32x4 aP[4][2], aQ[4][2];
#pragma unroll
    for (int er = 0; er < 4; ++er)
#pragma unroll
        for (int j = 0; j < 2; ++j) { aP[er][j] = (f32x4)0.f; aQ[er][j] = (f32x4)0.f; }

    const bf16* bp0 = w1t + (size_t)((wv * 2 + 0) * 16 + lr) * 256 + lg * 8;
    const bf16* bp1 = w1t + (size_t)((wv * 2 + 1) * 16 + lr) * 256 + lg * 8;
#pragma unroll
    for (int kk = 0; kk < 4; ++kk) {
        bf16x8 a[4];
#pragma unroll
        for (int er = 0; er < 4; ++er) {
            int sl = (kk * 4 + lg) ^ (lr & 7);
            a[er] = *(const bf16x8*)(hs + (er * 16 + lr) * 128 + sl * 8);
        }
        bf16x8 bP0 = *(const bf16x8*)(bp0 + kk * 32);
        bf16x8 bP1 = *(const bf16x8*)(bp1 + kk * 32);
        bf16x8 bQ0 = *(const bf16x8*)(bp0 + 128 + kk * 32);
        bf16x8 bQ1 = *(const bf16x8*)(bp1 + 128 + kk * 32);
#pragma unroll
        for (int er = 0; er < 4; ++er) {
            aP[er][0] = __builtin_amdgcn_mfma_f32_16x16x32_bf16(a[er], bP0, aP[er][0], 0, 0, 0);
            aP[er][1] = __builtin_amdgcn_mfma_f32_16x16x32_bf16(a[er], bP1, aP[er][1], 0, 0, 0);
            aQ[er][0] = __builtin_amdgcn_mfma_f32_16x16x32_bf16(a[er], bQ0, aQ[er][0], 0, 0, 0);
            aQ[er][1] = __builtin_amdgcn_mfma_f32_16x16x32_bf16(a[er], bQ1, aQ[er][1], 0, 0, 0);
        }
    }

    float bb0 = b1[(wv * 2 + 0) * 16 + lr];
    float bb1v = b1[(wv * 2 + 1) * 16 + lr];
#pragma unroll
    for (int er = 0; er < 4; ++er) {
#pragma unroll
        for (int j = 0; j < 2; ++j) {
            int feat = (wv * 2 + j) * 16 + lr;
            float bb = j ? bb1v : bb0;
#pragma unroll
            for (int r = 0; r < 4; ++r) {
                int node = nbase + er * 16 + lg * 4 + r;
                if (node < N_NODES) {
                    P[(size_t)node * H + feat] = (bf16)(aP[er][j][r] + bb);
                    Q[(size_t)node * H + feat] = (bf16)(aQ[er][j][r]);
                }
            }
        }
    }
}

// ---------------- gathers (CSR-contiguous; off holds run-ENDs after fill2) ----------------

// ef rows are fp8 e4m3 (128 B/row), UNSCALED; per-edge scale attw[slot] applied here
__global__ __launch_bounds__(256) void gather_h_kernel(
    const uchar* __restrict__ ef, const float* __restrict__ attw,
    const int* __restrict__ off, bf16* __restrict__ agg_bf) {
    int t = threadIdx.x, lane = t & 63, wv = t >> 6;
    int n = blockIdx.x * 4 + wv;
    if (n >= N_NODES) return;
    int st = (n == 0) ? 0 : off[n - 1];
    int dg = off[n] - st;
    const uchar* bp = ef + (size_t)st * 128 + lane * 2;
    const float* sp = attw + st;
    float s0 = 0.f, s1 = 0.f;
    for (int k = 0; k < dg; ++k) {
        uint v = __builtin_nontemporal_load((const ushort*)(bp + (size_t)k * 128));
        float sc = sp[k];  // broadcast across lanes
        f32x2 f = __builtin_amdgcn_cvt_pk_f32_fp8(v, false);
        s0 += f.x * sc;
        s1 += f.y * sc;
    }
    bf16x2 o;
    o[0] = (bf16)s0;   // 0.01 folded into attw
    o[1] = (bf16)s1;
    *(bf16x2*)(agg_bf + (size_t)n * H + lane * 2) = o;
}

__global__ __launch_bounds__(256) void gather_x_kernel(
    const float* __restrict__ trans, const int* __restrict__ off,
    const float* __restrict__ x, const float* __restrict__ nmask, float* __restrict__ outx) {
    int t = threadIdx.x, lane = t & 63, wv = t >> 6;
    int n = blockIdx.x * 4 + wv;
    if (n >= N_NODES) return;
    int st = (n == 0) ? 0 : off[n - 1];
    int dg = off[n] - st;
    float sx = 0.f, sy = 0.f, sz = 0.f;
    for (int k = lane; k < dg; k += 64) {
        const float* tp = trans + (size_t)(st + k) * 3;
        sx += tp[0];
        sy += tp[1];
        sz += tp[2];
    }
#pragma unroll
    for (int m = 1; m < 64; m <<= 1) {
        sx += __shfl_xor(sx, m);
        sy += __shfl_xor(sy, m);
        sz += __shfl_xor(sz, m);
    }
    if (lane == 0) {
        float nm = nmask[n];
        outx[n * 3 + 0] = (x[n * 3 + 0] + sx * 0.01f) * nm;
        outx[n * 3 + 1] = (x[n * 3 + 1] + sy * 0.01f) * nm;
        outx[n * 3 + 2] = (x[n * 3 + 2] + sz * 0.01f) * nm;
    }
}

// ---------------- MFMA helpers ----------------
// A layout (16x16x32 bf16): lane holds A[lane&15][(lane>>4)*8 + i]
// C/D layout (HW-verified): col = lane&15, row = (lane>>4)*4 + reg

template <int KCHUNKS, int ASTRIDE, int BSTRIDE>
DEV void wave_gemm(const bf16* A_lds, const bf16* __restrict__ Bt,
                   f32x4 (&acc)[4][2], int lr, int lg, int wv) {
#pragma unroll
    for (int kk = 0; kk < KCHUNKS; ++kk) {
        int ko = kk * 32 + lg * 8;
        bf16x8 a[4], b[2];
#pragma unroll
        for (int er = 0; er < 4; ++er)
            a[er] = *(const bf16x8*)(A_lds + (er * 16 + lr) * ASTRIDE + ko);
#pragma unroll
        for (int j = 0; j < 2; ++j)
            b[j] = *(const bf16x8*)(Bt + (size_t)((wv * 2 + j) * 16 + lr) * BSTRIDE + ko);
#pragma unroll
        for (int er = 0; er < 4; ++er)
#pragma unroll
            for (int j = 0; j < 2; ++j)
                acc[er][j] = __builtin_amdgcn_mfma_f32_16x16x32_bf16(a[er], b[j], acc[er][j], 0, 0, 0);
    }
}

DEV void epi_silu_store(const f32x4 (&acc)[4][2], const float* __restrict__ bias,
                        bf16* out_lds, int OSTRIDE, int lr, int lg, int wv) {
    float b0 = bias[(wv * 2 + 0) * 16 + lr];
    float b1 = bias[(wv * 2 + 1) * 16 + lr];
#pragma unroll
    for (int er = 0; er < 4; ++er) {
#pragma unroll
        for (int j = 0; j < 2; ++j) {
            float bb = j ? b1 : b0;
            int fcol = (wv * 2 + j) * 16 + lr;
#pragma unroll
            for (int r = 0; r < 4; ++r) {
                int rrow = er * 16 + lg * 4 + r;
                out_lds[rrow * OSTRIDE + fcol] = (bf16)fsilu(acc[er][j][r] + bb);
            }
        }
    }
}

// swizzled variant: [64][128] with 16B-slot XOR (slot ^= row&7)
DEV void epi_silu_store_swz(const f32x4 (&acc)[4][2], const float* __restrict__ bias,
                            bf16* out_lds, int lr, int lg, int wv) {
    float b0 = bias[(wv * 2 + 0) * 16 + lr];
    float b1 = bias[(wv * 2 + 1) * 16 + lr];
#pragma unroll
    for (int er = 0; er < 4; ++er) {
#pragma unroll
        for (int j = 0; j < 2; ++j) {
            float bb = j ? b1 : b0;
            int fcol = (wv * 2 + j) * 16 + lr;
#pragma unroll
            for (int r = 0; r < 4; ++r) {
                int rrow = er * 16 + lg * 4 + r;
                int sl = (fcol >> 3) ^ (rrow & 7);
                out_lds[rrow * 128 + sl * 8 + (fcol & 7)] = (bf16)fsilu(acc[er][j][r] + bb);
            }
        }
    }
}

// ---------------- edge / coord kernel ----------------
// Q[col] staged via global_load_lds into T (XOR swizzle); P[row] direct (L1-hot).
// Phase1: t1 = silu(P+Q+radial*w_r+eattr*w_e) in-place in T. GEMM2 -> mij -> T.
// Phase4: MFMA attention dot; fp8 ef store is UNSCALED and independent of the dot
// (issues before the part_l barrier, overlapping it); per-edge scale
// attw = sigmoid(part+b)*em*0.01 written separately and applied in gather_h.
// MODE 0: -> ef fp8 + attw. MODE 1: -> trans[slot][3] f32.
template <int MODE>
__global__ __launch_bounds__(256, 8) void edge_kernel(
    const bf16* __restrict__ P, const bf16* __restrict__ Q,
    const uint* __restrict__ rc_pm, const bf16* __restrict__ eaem_pm,
    const float* __restrict__ xg,
    const float* __restrict__ w_r, const float* __restrict__ w_e,
    const bf16* __restrict__ w2t, const float* __restrict__ b2,
    const float* __restrict__ avec, const float* __restrict__ abias,
    uchar* __restrict__ efout, float* __restrict__ attout, float* __restrict__ trans) {
    __shared__ __align__(16) bf16 T[64 * 128];   // Q staged -> t1 in place -> mij (swz)
    __shared__ __align__(16) float wr_l[128];
    __shared__ __align__(16) float we_l[128];
    __shared__ float part_l[64];

    int t = threadIdx.x, lane = t & 63, wv = t >> 6;
    int lr = lane & 15, lg = lane >> 4;
    int ebase = blockIdx.x * 64;
    int el = t >> 2, q = t & 3;

    {   // async stage Q[col]
        int rsub = lane >> 4;
        int slot = lane & 15;
#pragma unroll
        for (int u = 0; u < 4; ++u) {
            int r = wv * 16 + u * 4 + rsub;
            uint rcs = rc_pm[ebase + r];
            int nc = (int)(rcs & 0xffffu);
            int sl = slot ^ (r & 7);
            const bf16* gpc = Q + (size_t)nc * H + sl * 8;
            __builtin_amdgcn_global_load_lds(
                (const __attribute__((address_space(1))) void*)gpc,
                (__attribute__((address_space(3))) void*)&T[(wv * 16 + u * 4) * 128],
                16, 0, 0);
        }
    }
    if (t < 128) {
        wr_l[t] = w_r[t];
    } else {
        we_l[t - 128] = w_e[t - 128];
    }

    // per-edge meta
    uint rc = rc_pm[ebase + el];
    int rr = (int)(rc >> 16), cc = (int)(rc & 0xffffu);
    float dx = xg[rr * 3 + 0] - xg[cc * 3 + 0];
    float dy = xg[rr * 3 + 1] - xg[cc * 3 + 1];
    float dz = xg[rr * 3 + 2] - xg[cc * 3 + 2];
    float radial = dx * dx + dy * dy + dz * dz;
    uint eu = *(const uint*)(eaem_pm + (size_t)(ebase + el) * 2);
    bf16x2 ep = __builtin_bit_cast(bf16x2, eu);
    float eattr = (float)ep[0];
    float em = (float)ep[1];

    // P[row] fragments direct from global (L1-hot)
    bf16x8 pvr[4];
    const bf16* Pp = P + (size_t)rr * H + q * 32;
#pragma unroll
    for (int c = 0; c < 4; ++c) pvr[c] = *(const bf16x8*)(Pp + c * 8);

    __syncthreads();  // staging drained + LDS consts ready

    // ---- phase 1: t1 = silu(P+Q+radial*w_r+eattr*w_e), in-place in T ----
    f32x2 rad2 = {radial, radial};
    f32x2 ea2 = {eattr, eattr};
#pragma unroll
    for (int c = 0; c < 4; ++c) {
        int sl = (q * 4 + c) ^ (el & 7);
        bf16* ap = T + el * 128 + sl * 8;
        u32x4 qu = __builtin_bit_cast(u32x4, *(const bf16x8*)ap);
        u32x4 pu = __builtin_bit_cast(u32x4, pvr[c]);
        bf16x8 o;
#pragma unroll
        for (int k = 0; k < 4; ++k) {
            uint puk = pu[k], quk = qu[k];
            f32x2 p2 = {__uint_as_float(puk << 16), __uint_as_float(puk & 0xffff0000u)};
            f32x2 q2 = {__uint_as_float(quk << 16), __uint_as_float(quk & 0xffff0000u)};
            f32x2 w2 = *(const f32x2*)(wr_l + q * 32 + c * 8 + k * 2);
            f32x2 e2 = *(const f32x2*)(we_l + q * 32 + c * 8 + k * 2);
            f32x2 v = p2 + q2 + rad2 * w2 + ea2 * e2;
            o[2 * k + 0] = (bf16)fsilu(v.x);
            o[2 * k + 1] = (bf16)fsilu(v.y);
        }
        *(bf16x8*)ap = o;
    }
    __syncthreads();  // t1 ready

    // ---- phase 2: GEMM2 (A = t1 in T swz, B = w2t) ----
    f32x4 acc2[4][2];
#pragma unroll
    for (int er = 0; er < 4; ++er)
#pragma unroll
        for (int j = 0; j < 2; ++j) acc2[er][j] = (f32x4)0.f;
    {
        const bf16* cp0 = w2t + (size_t)((wv * 2 + 0) * 16 + lr) * 128 + lg * 8;
        const bf16* cp1 = w2t + (size_t)((wv * 2 + 1) * 16 + lr) * 128 + lg * 8;
#pragma unroll
        for (int kk = 0; kk < 4; ++kk) {
            bf16x8 a[4], b[2];
            b[0] = *(const bf16x8*)(cp0 + kk * 32);
            b[1] = *(const bf16x8*)(cp1 + kk * 32);
#pragma unroll
            for (int er = 0; er < 4; ++er) {
                int sl = (kk * 4 + lg) ^ (lr & 7);
                a[er] = *(const bf16x8*)(T + (er * 16 + lr) * 128 + sl * 8);
            }
#pragma unroll
            for (int er = 0; er < 4; ++er)
#pragma unroll
                for (int j = 0; j < 2; ++j)
                    acc2[er][j] = __builtin_amdgcn_mfma_f32_16x16x32_bf16(a[er], b[j], acc2[er][j], 0, 0, 0);
        }
    }
    __syncthreads();  // all GEMM2 reads of T done

    // ---- phase 3: mij = silu(GEMM2 + b2) -> T (swizzled) ----
    epi_silu_store_swz(acc2, b2, T, lr, lg, wv);
    __syncthreads();

    // ---- phase 4a: attention dot via MFMA (B = avec in col 0) ----
    f32x4 dacc = (f32x4)0.f;
#pragma unroll
    for (int kk = 0; kk < 4; ++kk) {
        int sl = (kk * 4 + lg) ^ (lr & 7);
        bf16x8 a = *(const bf16x8*)(T + (wv * 16 + lr) * 128 + sl * 8);
        bf16x8 b = (bf16x8)(bf16)0.f;
        if (lr == 0) {
#pragma unroll
            for (int i = 0; i < 8; ++i) b[i] = (bf16)avec[kk * 32 + lg * 8 + i];
        }
        dacc = __builtin_amdgcn_mfma_f32_16x16x32_bf16(a, b, dacc, 0, 0, 0);
    }

    // ---- phase 4b: fp8 ef store (UNSCALED, independent of dot -> overlaps it) ----
    if (MODE == 0) {
        uchar* edst = efout + (size_t)(ebase + el) * 128 + q * 32;
#pragma unroll
        for (int cpair = 0; cpair < 2; ++cpair) {
            u32x4 wout;
#pragma unroll
            for (int cc = 0; cc < 2; ++cc) {
                int c = cpair * 2 + cc;
                int sl = (q * 4 + c) ^ (el & 7);
                u32x4 mu = __builtin_bit_cast(u32x4, *(const bf16x8*)(T + el * 128 + sl * 8));
                uint w0 = 0, w1 = 0;
                {
                    uint m0 = mu[0], m1 = mu[1];
                    w0 = __builtin_amdgcn_cvt_pk_fp8_f32(
                        __uint_as_float(m0 << 16), __uint_as_float(m0 & 0xffff0000u), w0, false);
                    w0 = __builtin_amdgcn_cvt_pk_fp8_f32(
                        __uint_as_float(m1 << 16), __uint_as_float(m1 & 0xffff0000u), w0, true);
                }
                {
                    uint m2 = mu[2], m3 = mu[3];
                    w1 = __builtin_amdgcn_cvt_pk_fp8_f32(
                        __uint_as_float(m2 << 16), __uint_as_float(m2 & 0xffff0000u), w1, false);
                    w1 = __builtin_amdgcn_cvt_pk_fp8_f32(
                        __uint_as_float(m3 << 16), __uint_as_float(m3 & 0xffff0000u), w1, true);
                }
                wout[cc * 2 + 0] = w0;
                wout[cc * 2 + 1] = w1;
            }
            __builtin_nontemporal_store(wout, (u32x4*)(edst + cpair * 16));
        }
    }

    if (lr == 0) {
#pragma unroll
        for (int r = 0; r < 4; ++r) part_l[wv * 16 + lg * 4 + r] = dacc[r];
    }
    __syncthreads();

    // ---- phase 4c: per-edge scalar output ----
    if (MODE == 0) {
        if (q == 0) {
            float part = part_l[el];
            attout[ebase + el] = fsigmoid(part + abias[0]) * em * 0.01f;
        }
    } else {
        if (q == 0) {
            float part = part_l[el];
            float inv = 1.f / (sqrtf(radial + 1e-8f) + 1.f);
            float s = part * em * inv;
            int sI = ebase + el;
            trans[sI * 3 + 0] = dx * s;
            trans[sI * 3 + 1] = dy * s;
            trans[sI * 3 + 2] = dz * s;
        }
    }
}

// ---------------- node MLP kernel ----------------
__global__ __launch_bounds__(256, 2) void node_kernel(
    float* __restrict__ h_cur, const bf16* __restrict__ agg_bf,
    const bf16* __restrict__ w1t, const float* __restrict__ b1,
    const bf16* __restrict__ w2t, const float* __restrict__ b2,
    const float* __restrict__ nmask) {
    constexpr int SRN = 264;
    constexpr int TRN = 136;
    __shared__ __align__(16) bf16 ninp[64 * SRN];
    __shared__ __align__(16) bf16 t1[64 * TRN];

    int t = threadIdx.x, lane = t & 63, wv = t >> 6;
    int lr = lane & 15, lg = lane >> 4;
    int nbase = blockIdx.x * 64;

    {   // stage ninp = [bf16(h), agg_bf]
        int nl = t >> 2, q = t & 3;
        int node = nbase + nl;
        bf16* dst = ninp + nl * SRN;
        if (node < N_NODES) {
            const float4* hr = (const float4*)(h_cur + (size_t)node * H);
            const bf16* ar = agg_bf + (size_t)node * H;
#pragma unroll
            for (int pp = 0; pp < 8; ++pp) {
                int ch = pp * 4 + q;
                float4 v = hr[ch];
                dst[ch * 4 + 0] = (bf16)v.x; dst[ch * 4 + 1] = (bf16)v.y;
                dst[ch * 4 + 2] = (bf16)v.z; dst[ch * 4 + 3] = (bf16)v.w;
            }
#pragma unroll
            for (int pp = 0; pp < 4; ++pp) {
                int ch = pp * 4 + q;
                *(bf16x8*)(dst + 128 + ch * 8) = *(const bf16x8*)(ar + ch * 8);
            }
        } else {
#pragma unroll
            for (int pp = 0; pp < 8; ++pp) {
                int ch = pp * 4 + q;
#pragma unroll
                for (int k = 0; k < 4; ++k) {
                    dst[ch * 4 + k] = (bf16)0.f;
                    dst[128 + ch * 4 + k] = (bf16)0.f;
                }
            }
        }
    }
    __syncthreads();

    f32x4 acc[4][2];
#pragma unroll
    for (int er = 0; er < 4; ++er)
#pragma unroll
        for (int j = 0; j < 2; ++j) acc[er][j] = (f32x4)0.f;
    wave_gemm<8, SRN, 256>(ninp, w1t, acc, lr, lg, wv);
    epi_silu_store(acc, b1, t1, TRN, lr, lg, wv);
    __syncthreads();

    f32x4 acc2[4][2];
#pragma unroll
    for (int er = 0; er < 4; ++er)
#pragma unroll
        for (int j = 0; j < 2; ++j) acc2[er][j] = (f32x4)0.f;
    wave_gemm<4, TRN, 128>(t1, w2t, acc2, lr, lg, wv);

    float bb0 = b2[(wv * 2 + 0) * 16 + lr];
    float bb1 = b2[(wv * 2 + 1) * 16 + lr];
#pragma unroll
    for (int er = 0; er < 4; ++er) {
#pragma unroll
        for (int j = 0; j < 2; ++j) {
            float bb = j ? bb1 : bb0;
            int feat = (wv * 2 + j) * 16 + lr;
#pragma unroll
            for (int r = 0; r < 4; ++r) {
                int node = nbase + er * 16 + lg * 4 + r;
                if (node < N_NODES) {
                    size_t idx = (size_t)node * H + feat;
                    float nm = nmask[node];
                    h_cur[idx] = (h_cur[idx] + acc2[er][j][r] + bb) * nm;  // fp32 residual
                }
            }
        }
    }
}

// ---------------- launch ----------------
extern "C" void kernel_launch(void* const* d_in, const int* in_sizes, int n_in,
                              void* d_out, int out_size, void* d_ws, size_t ws_size,
                              hipStream_t stream) {
    (void)in_sizes; (void)n_in; (void)out_size; (void)ws_size;
    const float* h_in  = (const float*)d_in[0];
    const float* x_in  = (const float*)d_in[1];
    const int*   ei    = (const int*)d_in[2];
    const float* eattr = (const float*)d_in[3];
    const float* nmask = (const float*)d_in[4];
    const float* emask = (const float*)d_in[5];
    const float* e_w1  = (const float*)d_in[6];
    const float* e_b1  = (const float*)d_in[7];
    const float* e_w2  = (const float*)d_in[8];
    const float* e_b2  = (const float*)d_in[9];
    const float* a_w   = (const float*)d_in[10];
    const float* a_b   = (const float*)d_in[11];
    const float* n_w1  = (const float*)d_in[12];
    const float* n_b1  = (const float*)d_in[13];
    const float* n_w2  = (const float*)d_in[14];
    const float* n_b2  = (const float*)d_in[15];
    const float* c_w1  = (const float*)d_in[16];
    const float* c_b1  = (const float*)d_in[17];
    const float* c_w2  = (const float*)d_in[18];
    const float* c_b2  = (const float*)d_in[19];
    const float* c_w3  = (const float*)d_in[20];
    float* out = (float*)d_out;

    char* p = (char*)d_ws;
    auto alloc = [&](size_t bytes) { char* r = p; p += (bytes + 255) & ~(size_t)255; return r; };
    float* h_cur  = (float*)alloc((size_t)N_NODES * H * 4);     // 25.6 MB
    bf16*  Pb     = (bf16*) alloc((size_t)N_NODES * H * 2);     // 12.8 MB
    bf16*  Qb     = (bf16*) alloc((size_t)N_NODES * H * 2);     // 12.8 MB (agg aliases Q)
    bf16*  agg_bf = Qb;
    uchar* ef     = (uchar*)alloc((size_t)N_EDGES * 128);       // 102.4 MB fp8, slot-indexed
    float* trans  = (float*)ef;                                 // alias: ef dead before edge<1>
    float* attw   = (float*)alloc((size_t)N_EDGES * 4);         // 3.2 MB per-edge scale
    int*   deg    = (int*)  alloc((size_t)N_NODES * 4);
    int*   off    = (int*)  alloc((size_t)N_NODES * 4);
    int*   bsum   = (int*)  alloc((size_t)NB_SCAN * 4);
    uint*  rc_pm  = (uint*) alloc((size_t)N_EDGES * 4);         // slot-ordered row<<16|col
    bf16*  eaem_pm= (bf16*) alloc((size_t)N_EDGES * 2 * 2);     // slot-ordered {eattr, emask}
    bf16*  e_w1t  = (bf16*) alloc((size_t)2 * 128 * 256 * 2);
    bf16*  e_w2t  = (bf16*) alloc((size_t)2 * 128 * 128 * 2);
    bf16*  n_w1t  = (bf16*) alloc((size_t)2 * 128 * 256 * 2);
    bf16*  n_w2t  = (bf16*) alloc((size_t)2 * 128 * 128 * 2);
    bf16*  c_w1t  = (bf16*) alloc((size_t)128 * 256 * 2);
    bf16*  c_w2t  = (bf16*) alloc((size_t)128 * 128 * 2);
    // total ~165 MB

    auto tp = [&](bf16* dst, const float* src, int K, int KP) {
        int tot = 128 * KP;
        transpose_pad_kernel<<<(tot + 255) / 256, 256, 0, stream>>>(dst, src, K, 128, KP);
    };
    tp(e_w1t, e_w1, 258, 256);               tp(e_w1t + 128 * 256, e_w1 + 258 * 128, 258, 256);
    tp(e_w2t, e_w2, 128, 128);               tp(e_w2t + 128 * 128, e_w2 + 128 * 128, 128, 128);
    tp(n_w1t, n_w1, 256, 256);               tp(n_w1t + 128 * 256, n_w1 + 256 * 128, 256, 256);
    tp(n_w2t, n_w2, 128, 128);               tp(n_w2t + 128 * 128, n_w2 + 128 * 128, 128, 128);
    tp(c_w1t, c_w1, 258, 256);
    tp(c_w2t, c_w2, 128, 128);

    h_init_kernel<<<(N_NODES * H + 255) / 256, 256, 0, stream>>>(h_in, h_cur, N_NODES * H);

    // ---- CSR build + slot-ordered packed metadata ----
    hipMemsetAsync(deg, 0, (size_t)N_NODES * 4, stream);
    count_kernel<<<(N_EDGES + 255) / 256, 256, 0, stream>>>(ei, deg);
    scan1_kernel<<<NB_SCAN, 256, 0, stream>>>(deg, off, bsum);
    scan2_kernel<<<1, 256, 0, stream>>>(bsum);
    scan3_kernel<<<NB_SCAN, 256, 0, stream>>>(off, bsum);
    fill2_kernel<<<(N_EDGES + 255) / 256, 256, 0, stream>>>(
        ei, eattr, emask, off, rc_pm, eaem_pm);

    int ngrid = (N_NODES + 3) / 4;
    int pqgrid = (N_NODES + 63) / 64;
    for (int i = 0; i < 2; ++i) {
        pq_kernel<<<pqgrid, 256, 0, stream>>>(
            h_cur, e_w1t + (size_t)i * 128 * 256, e_b1 + i * H, Pb, Qb);
        edge_kernel<0><<<N_EDGES / 64, 256, 0, stream>>>(
            Pb, Qb, rc_pm, eaem_pm, x_in,
            e_w1 + (size_t)i * 258 * 128 + 256 * 128,   // w_r
            e_w1 + (size_t)i * 258 * 128 + 257 * 128,   // w_e
            e_w2t + (size_t)i * 128 * 128, e_b2 + i * H,
            a_w + i * H, a_b + i, ef, attw, nullptr);
        gather_h_kernel<<<ngrid, 256, 0, stream>>>(ef, attw, off, agg_bf);  // into Qb (dead)
        node_kernel<<<(N_NODES + 63) / 64, 256, 0, stream>>>(
            h_cur, agg_bf,
            n_w1t + (size_t)i * 128 * 256, n_b1 + i * H,
            n_w2t + (size_t)i * 128 * 128, n_b2 + i * H, nmask);
    }
    // coord path
    pq_kernel<<<pqgrid, 256, 0, stream>>>(h_cur, c_w1t, c_b1, Pb, Qb);
    edge_kernel<1><<<N_EDGES / 64, 256, 0, stream>>>(
        Pb, Qb, rc_pm, eaem_pm, x_in,
        c_w1 + 256 * 128, c_w1 + 257 * 128,
        c_w2t, c_b2, c_w3, nullptr, nullptr, nullptr, trans);
    gather_x_kernel<<<ngrid, 256, 0, stream>>>(trans, off, x_in, nmask,
                                               out + (size_t)N_NODES * H);

    out_h_kernel<<<(N_NODES * H + 255) / 256, 256, 0, stream>>>(h_cur, nmask, out);
}

// Round 20
// 805.509 us; speedup vs baseline: 1.0569x; 1.0569x over previous
//
#include <hip/hip_runtime.h>
#include <hip/hip_bf16.h>
#include <math.h>
#include <string.h>

#define DEV __device__ __forceinline__

typedef __bf16 bf16;
typedef bf16 bf16x8 __attribute__((ext_vector_type(8)));
typedef bf16 bf16x2 __attribute__((ext_vector_type(2)));
typedef float f32x4 __attribute__((ext_vector_type(4)));
typedef float f32x2 __attribute__((ext_vector_type(2)));
typedef unsigned int uint;
typedef unsigned char uchar;
typedef unsigned short ushort;

constexpr int N_NODES = 50000;
constexpr int N_EDGES = 800000;
constexpr int H = 128;
constexpr int NB_SCAN = (N_NODES + 255) / 256;  // 196

DEV float fsilu(float x) { return x / (1.f + __expf(-x)); }
DEV float fsigmoid(float x) { return 1.f / (1.f + __expf(-x)); }

// ---------------- small prep kernels ----------------

__global__ void transpose_pad_kernel(bf16* __restrict__ dst, const float* __restrict__ src,
                                     int K, int Nf, int KP) {
    int idx = blockIdx.x * 256 + threadIdx.x;
    if (idx >= Nf * KP) return;
    int n = idx / KP, k = idx - n * KP;
    dst[idx] = (k < K) ? (bf16)src[k * Nf + n] : (bf16)0.f;
}

__global__ void h_init_kernel(const float* __restrict__ h, float* __restrict__ h_cur, int n) {
    int i = blockIdx.x * 256 + threadIdx.x;
    if (i < n) h_cur[i] = h[i];
}

__global__ void out_h_kernel(const float* __restrict__ h_cur, const float* __restrict__ nmask,
                             float* __restrict__ out) {
    int i = blockIdx.x * 256 + threadIdx.x;
    if (i < N_NODES * H) out[i] = h_cur[i] * nmask[i >> 7];
}

// ---------------- CSR build (group edges by row) ----------------

__global__ void count_kernel(const int* __restrict__ ei, int* __restrict__ deg) {
    int e = blockIdx.x * 256 + threadIdx.x;
    if (e < N_EDGES) atomicAdd(&deg[ei[e]], 1);
}

__global__ void scan1_kernel(const int* __restrict__ deg, int* __restrict__ off,
                             int* __restrict__ bsum) {
    __shared__ int s[256];
    int t = threadIdx.x, i = blockIdx.x * 256 + t;
    int v = (i < N_NODES) ? deg[i] : 0;
    s[t] = v;
    __syncthreads();
#pragma unroll
    for (int st = 1; st < 256; st <<= 1) {
        int x = (t >= st) ? s[t - st] : 0;
        __syncthreads();
        s[t] += x;
        __syncthreads();
    }
    if (i < N_NODES) off[i] = s[t] - v;
    if (t == 255) bsum[blockIdx.x] = s[255];
}

__global__ void scan2_kernel(int* __restrict__ bsum) {
    __shared__ int s[256];
    int t = threadIdx.x;
    int v = (t < NB_SCAN) ? bsum[t] : 0;
    s[t] = v;
    __syncthreads();
#pragma unroll
    for (int st = 1; st < 256; st <<= 1) {
        int x = (t >= st) ? s[t - st] : 0;
        __syncthreads();
        s[t] += x;
        __syncthreads();
    }
    if (t < NB_SCAN) bsum[t] = s[t] - v;
}

__global__ void scan3_kernel(int* __restrict__ off, const int* __restrict__ bsum) {
    int i = blockIdx.x * 256 + threadIdx.x;
    if (i >= N_NODES) return;
    off[i] += bsum[blockIdx.x];
}

__global__ void fill2_kernel(const int* __restrict__ ei, const float* __restrict__ eattr,
                             const float* __restrict__ emask, int* __restrict__ off,
                             uint* __restrict__ rc_pm, bf16* __restrict__ eaem_pm) {
    int e = blockIdx.x * 256 + threadIdx.x;
    if (e >= N_EDGES) return;
    int r = ei[e], c = ei[N_EDGES + e];
    int slot = atomicAdd(&off[r], 1);
    rc_pm[slot] = ((uint)r << 16) | (uint)c;
    eaem_pm[(size_t)slot * 2 + 0] = (bf16)eattr[e];
    eaem_pm[(size_t)slot * 2 + 1] = (bf16)emask[e];
}

// ---------------- per-node P/Q precompute ----------------
__global__ __launch_bounds__(256, 2) void pq_kernel(
    const float* __restrict__ h_cur, const bf16* __restrict__ w1t,
    const float* __restrict__ b1, bf16* __restrict__ P, bf16* __restrict__ Q) {
    __shared__ __align__(16) bf16 hs[64 * 128];
    int t = threadIdx.x, lane = t & 63, wv = t >> 6;
    int lr = lane & 15, lg = lane >> 4;
    int nbase = blockIdx.x * 64;

    {   // stage bf16(h) swizzled
        int nl = t >> 2, q = t & 3;
        int node = nbase + nl;
        if (node < N_NODES) {
            const float4* hr = (const float4*)(h_cur + (size_t)node * H);
#pragma unroll
            for (int c = 0; c < 4; ++c) {
                float4 v0 = hr[q * 8 + c * 2];
                float4 v1 = hr[q * 8 + c * 2 + 1];
                bf16x8 o;
                o[0] = (bf16)v0.x; o[1] = (bf16)v0.y; o[2] = (bf16)v0.z; o[3] = (bf16)v0.w;
                o[4] = (bf16)v1.x; o[5] = (bf16)v1.y; o[6] = (bf16)v1.z; o[7] = (bf16)v1.w;
                int sl = (q * 4 + c) ^ (nl & 7);
                *(bf16x8*)(hs + nl * 128 + sl * 8) = o;
            }
        } else {
#pragma unroll
            for (int c = 0; c < 4; ++c) {
                int sl = (q * 4 + c) ^ (nl & 7);
                *(bf16x8*)(hs + nl * 128 + sl * 8) = (bf16x8)(bf16)0.f;
            }
        }
    }
    __syncthreads();

    f32x4 aP[4][2], aQ[4][2];
#pragma unroll
    for (int er = 0; er < 4; ++er)
#pragma unroll
        for (int j = 0; j < 2; ++j) { aP[er][j] = (f32x4)0.f; aQ[er][j] = (f32x4)0.f; }

    const bf16* bp0 = w1t + (size_t)((wv * 2 + 0) * 16 + lr) * 256 + lg * 8;
    const bf16* bp1 = w1t + (size_t)((wv * 2 + 1) * 16 + lr) * 256 + lg * 8;
#pragma unroll
    for (int kk = 0; kk < 4; ++kk) {
        bf16x8 a[4];
#pragma unroll
        for (int er = 0; er < 4; ++er) {
            int sl = (kk * 4 + lg) ^ (lr & 7);
            a[er] = *(const bf16x8*)(hs + (er * 16 + lr) * 128 + sl * 8);
        }
        bf16x8 bP0 = *(const bf16x8*)(bp0 + kk * 32);
        bf16x8 bP1 = *(const bf16x8*)(bp1 + kk * 32);
        bf16x8 bQ0 = *(const bf16x8*)(bp0 + 128 + kk * 32);
        bf16x8 bQ1 = *(const bf16x8*)(bp1 + 128 + kk * 32);
#pragma unroll
        for (int er = 0; er < 4; ++er) {
            aP[er][0] = __builtin_amdgcn_mfma_f32_16x16x32_bf16(a[er], bP0, aP[er][0], 0, 0, 0);
            aP[er][1] = __builtin_amdgcn_mfma_f32_16x16x32_bf16(a[er], bP1, aP[er][1], 0, 0, 0);
            aQ[er][0] = __builtin_amdgcn_mfma_f32_16x16x32_bf16(a[er], bQ0, aQ[er][0], 0, 0, 0);
            aQ[er][1] = __builtin_amdgcn_mfma_f32_16x16x32_bf16(a[er], bQ1, aQ[er][1], 0, 0, 0);
        }
    }

    float bb0 = b1[(wv * 2 + 0) * 16 + lr];
    float bb1v = b1[(wv * 2 + 1) * 16 + lr];
#pragma unroll
    for (int er = 0; er < 4; ++er) {
#pragma unroll
        for (int j = 0; j < 2; ++j) {
            int feat = (wv * 2 + j) * 16 + lr;
            float bb = j ? bb1v : bb0;
#pragma unroll
            for (int r = 0; r < 4; ++r) {
                int node = nbase + er * 16 + lg * 4 + r;
                if (node < N_NODES) {
                    P[(size_t)node * H + feat] = (bf16)(aP[er][j][r] + bb);
                    Q[(size_t)node * H + feat] = (bf16)(aQ[er][j][r]);
                }
            }
        }
    }
}

// ---------------- gathers (CSR-contiguous; off holds run-ENDs after fill2) ----------------

// ef rows are fp8 e4m3 (128 B/row); lane decodes 2 feats via cvt_pk_f32_fp8
__global__ __launch_bounds__(256) void gather_h_kernel(
    const uchar* __restrict__ ef, const int* __restrict__ off, bf16* __restrict__ agg_bf) {
    int t = threadIdx.x, lane = t & 63, wv = t >> 6;
    int n = blockIdx.x * 4 + wv;
    if (n >= N_NODES) return;
    int st = (n == 0) ? 0 : off[n - 1];
    int dg = off[n] - st;
    const uchar* bp = ef + (size_t)st * 128 + lane * 2;
    float s0 = 0.f, s1 = 0.f;
    for (int k = 0; k < dg; ++k) {
        uint v = *(const ushort*)(bp + (size_t)k * 128);
        f32x2 f = __builtin_amdgcn_cvt_pk_f32_fp8(v, false);
        s0 += f.x;
        s1 += f.y;
    }
    bf16x2 o;
    o[0] = (bf16)(s0 * 0.01f);
    o[1] = (bf16)(s1 * 0.01f);
    *(bf16x2*)(agg_bf + (size_t)n * H + lane * 2) = o;
}

__global__ __launch_bounds__(256) void gather_x_kernel(
    const float* __restrict__ trans, const int* __restrict__ off,
    const float* __restrict__ x, const float* __restrict__ nmask, float* __restrict__ outx) {
    int t = threadIdx.x, lane = t & 63, wv = t >> 6;
    int n = blockIdx.x * 4 + wv;
    if (n >= N_NODES) return;
    int st = (n == 0) ? 0 : off[n - 1];
    int dg = off[n] - st;
    float sx = 0.f, sy = 0.f, sz = 0.f;
    for (int k = lane; k < dg; k += 64) {
        const float* tp = trans + (size_t)(st + k) * 3;
        sx += tp[0];
        sy += tp[1];
        sz += tp[2];
    }
#pragma unroll
    for (int m = 1; m < 64; m <<= 1) {
        sx += __shfl_xor(sx, m);
        sy += __shfl_xor(sy, m);
        sz += __shfl_xor(sz, m);
    }
    if (lane == 0) {
        float nm = nmask[n];
        outx[n * 3 + 0] = (x[n * 3 + 0] + sx * 0.01f) * nm;
        outx[n * 3 + 1] = (x[n * 3 + 1] + sy * 0.01f) * nm;
        outx[n * 3 + 2] = (x[n * 3 + 2] + sz * 0.01f) * nm;
    }
}

// ---------------- MFMA helpers ----------------
// A layout (16x16x32 bf16): lane holds A[lane&15][(lane>>4)*8 + i]
// C/D layout (HW-verified): col = lane&15, row = (lane>>4)*4 + reg

template <int KCHUNKS, int ASTRIDE, int BSTRIDE>
DEV void wave_gemm(const bf16* A_lds, const bf16* __restrict__ Bt,
                   f32x4 (&acc)[4][2], int lr, int lg, int wv) {
#pragma unroll
    for (int kk = 0; kk < KCHUNKS; ++kk) {
        int ko = kk * 32 + lg * 8;
        bf16x8 a[4], b[2];
#pragma unroll
        for (int er = 0; er < 4; ++er)
            a[er] = *(const bf16x8*)(A_lds + (er * 16 + lr) * ASTRIDE + ko);
#pragma unroll
        for (int j = 0; j < 2; ++j)
            b[j] = *(const bf16x8*)(Bt + (size_t)((wv * 2 + j) * 16 + lr) * BSTRIDE + ko);
#pragma unroll
        for (int er = 0; er < 4; ++er)
#pragma unroll
            for (int j = 0; j < 2; ++j)
                acc[er][j] = __builtin_amdgcn_mfma_f32_16x16x32_bf16(a[er], b[j], acc[er][j], 0, 0, 0);
    }
}

DEV void epi_silu_store(const f32x4 (&acc)[4][2], const float* __restrict__ bias,
                        bf16* out_lds, int OSTRIDE, int lr, int lg, int wv) {
    float b0 = bias[(wv * 2 + 0) * 16 + lr];
    float b1 = bias[(wv * 2 + 1) * 16 + lr];
#pragma unroll
    for (int er = 0; er < 4; ++er) {
#pragma unroll
        for (int j = 0; j < 2; ++j) {
            float bb = j ? b1 : b0;
            int fcol = (wv * 2 + j) * 16 + lr;
#pragma unroll
            for (int r = 0; r < 4; ++r) {
                int rrow = er * 16 + lg * 4 + r;
                out_lds[rrow * OSTRIDE + fcol] = (bf16)fsilu(acc[er][j][r] + bb);
            }
        }
    }
}

// swizzled variant: [64][128] with 16B-slot XOR (slot ^= row&7)
DEV void epi_silu_store_swz(const f32x4 (&acc)[4][2], const float* __restrict__ bias,
                            bf16* out_lds, int lr, int lg, int wv) {
    float b0 = bias[(wv * 2 + 0) * 16 + lr];
    float b1 = bias[(wv * 2 + 1) * 16 + lr];
#pragma unroll
    for (int er = 0; er < 4; ++er) {
#pragma unroll
        for (int j = 0; j < 2; ++j) {
            float bb = j ? b1 : b0;
            int fcol = (wv * 2 + j) * 16 + lr;
#pragma unroll
            for (int r = 0; r < 4; ++r) {
                int rrow = er * 16 + lg * 4 + r;
                int sl = (fcol >> 3) ^ (rrow & 7);
                out_lds[rrow * 128 + sl * 8 + (fcol & 7)] = (bf16)fsilu(acc[er][j][r] + bb);
            }
        }
    }
}

// ---------------- edge / coord kernel ----------------
// Q[col] staged via global_load_lds into T (XOR swizzle); P[row] direct (L1-hot,
// CSR-sorted). Phase1: t1 = silu(P+Q+radial*w_r+eattr*w_e) in-place in T (packed
// f32x2 math). GEMM2 -> mij -> T. Attention dot via MFMA (B = avec in col 0),
// result scattered through part_l. Output ef in FP8 e4m3 (halved HBM write).
// LDS ~18 KB -> 8 blocks/CU. MODE 0: -> ef[slot][128] fp8. MODE 1: -> trans[slot][3] f32.
template <int MODE>
__global__ __launch_bounds__(256, 8) void edge_kernel(
    const bf16* __restrict__ P, const bf16* __restrict__ Q,
    const uint* __restrict__ rc_pm, const bf16* __restrict__ eaem_pm,
    const float* __restrict__ xg,
    const float* __restrict__ w_r, const float* __restrict__ w_e,
    const bf16* __restrict__ w2t, const float* __restrict__ b2,
    const float* __restrict__ avec, const float* __restrict__ abias,
    uchar* __restrict__ efout, float* __restrict__ trans) {
    __shared__ __align__(16) bf16 T[64 * 128];   // Q staged -> t1 in place -> mij (swz)
    __shared__ __align__(16) float wr_l[128];
    __shared__ __align__(16) float we_l[128];
    __shared__ float part_l[64];

    int t = threadIdx.x, lane = t & 63, wv = t >> 6;
    int lr = lane & 15, lg = lane >> 4;
    int ebase = blockIdx.x * 64;
    int el = t >> 2, q = t & 3;

    {   // async stage Q[col]: each instr writes 4 rows x 256B = 1024B linear LDS
        int rsub = lane >> 4;
        int slot = lane & 15;
#pragma unroll
        for (int u = 0; u < 4; ++u) {
            int r = wv * 16 + u * 4 + rsub;
            uint rcs = rc_pm[ebase + r];
            int nc = (int)(rcs & 0xffffu);
            int sl = slot ^ (r & 7);
            const bf16* gpc = Q + (size_t)nc * H + sl * 8;
            __builtin_amdgcn_global_load_lds(
                (const __attribute__((address_space(1))) void*)gpc,
                (__attribute__((address_space(3))) void*)&T[(wv * 16 + u * 4) * 128],
                16, 0, 0);
        }
    }
    if (t < 128) {
        wr_l[t] = w_r[t];
    } else {
        we_l[t - 128] = w_e[t - 128];
    }

    // per-edge meta in registers
    uint rc = rc_pm[ebase + el];
    int rr = (int)(rc >> 16), cc = (int)(rc & 0xffffu);
    float dx = xg[rr * 3 + 0] - xg[cc * 3 + 0];
    float dy = xg[rr * 3 + 1] - xg[cc * 3 + 1];
    float dz = xg[rr * 3 + 2] - xg[cc * 3 + 2];
    float radial = dx * dx + dy * dy + dz * dz;
    uint eu = *(const uint*)(eaem_pm + (size_t)(ebase + el) * 2);
    bf16x2 ep = __builtin_bit_cast(bf16x2, eu);
    float eattr = (float)ep[0];
    float em = (float)ep[1];

    // P[row] fragments direct from global (L1-hot)
    bf16x8 pvr[4];
    const bf16* Pp = P + (size_t)rr * H + q * 32;
#pragma unroll
    for (int c = 0; c < 4; ++c) pvr[c] = *(const bf16x8*)(Pp + c * 8);

    __syncthreads();  // staging drained + LDS consts ready

    // ---- phase 1: t1 = silu(P+Q+radial*w_r+eattr*w_e), in-place in T (pk math) ----
    f32x2 rad2 = {radial, radial};
    f32x2 ea2 = {eattr, eattr};
#pragma unroll
    for (int c = 0; c < 4; ++c) {
        int sl = (q * 4 + c) ^ (el & 7);
        bf16* ap = T + el * 128 + sl * 8;
        uint4 qu = __builtin_bit_cast(uint4, *(const bf16x8*)ap);
        uint4 pu = __builtin_bit_cast(uint4, pvr[c]);
        bf16x8 o;
#pragma unroll
        for (int k = 0; k < 4; ++k) {
            uint puk = (&pu.x)[k], quk = (&qu.x)[k];
            f32x2 p2 = {__uint_as_float(puk << 16), __uint_as_float(puk & 0xffff0000u)};
            f32x2 q2 = {__uint_as_float(quk << 16), __uint_as_float(quk & 0xffff0000u)};
            f32x2 w2 = *(const f32x2*)(wr_l + q * 32 + c * 8 + k * 2);
            f32x2 e2 = *(const f32x2*)(we_l + q * 32 + c * 8 + k * 2);
            f32x2 v = p2 + q2 + rad2 * w2 + ea2 * e2;
            o[2 * k + 0] = (bf16)fsilu(v.x);
            o[2 * k + 1] = (bf16)fsilu(v.y);
        }
        *(bf16x8*)ap = o;   // same row, same slot: group-private, no hazard
    }
    __syncthreads();  // t1 ready

    // ---- phase 2: GEMM2 (A = t1 in T swz, B = w2t) ----
    f32x4 acc2[4][2];
#pragma unroll
    for (int er = 0; er < 4; ++er)
#pragma unroll
        for (int j = 0; j < 2; ++j) acc2[er][j] = (f32x4)0.f;
    {
        const bf16* cp0 = w2t + (size_t)((wv * 2 + 0) * 16 + lr) * 128 + lg * 8;
        const bf16* cp1 = w2t + (size_t)((wv * 2 + 1) * 16 + lr) * 128 + lg * 8;
#pragma unroll
        for (int kk = 0; kk < 4; ++kk) {
            bf16x8 a[4], b[2];
            b[0] = *(const bf16x8*)(cp0 + kk * 32);
            b[1] = *(const bf16x8*)(cp1 + kk * 32);
#pragma unroll
            for (int er = 0; er < 4; ++er) {
                int sl = (kk * 4 + lg) ^ (lr & 7);
                a[er] = *(const bf16x8*)(T + (er * 16 + lr) * 128 + sl * 8);
            }
#pragma unroll
            for (int er = 0; er < 4; ++er)
#pragma unroll
                for (int j = 0; j < 2; ++j)
                    acc2[er][j] = __builtin_amdgcn_mfma_f32_16x16x32_bf16(a[er], b[j], acc2[er][j], 0, 0, 0);
        }
    }
    __syncthreads();  // all GEMM2 reads of T done -> safe to overwrite

    // ---- phase 3: mij = silu(GEMM2 + b2) -> T (swizzled) ----
    epi_silu_store_swz(acc2, b2, T, lr, lg, wv);
    __syncthreads();

    // ---- phase 4a: attention dot via MFMA. Wave wv handles rows [wv*16, wv*16+16).
    {
        f32x4 dacc = (f32x4)0.f;
#pragma unroll
        for (int kk = 0; kk < 4; ++kk) {
            int sl = (kk * 4 + lg) ^ (lr & 7);
            bf16x8 a = *(const bf16x8*)(T + (wv * 16 + lr) * 128 + sl * 8);
            bf16x8 b = (bf16x8)(bf16)0.f;
            if (lr == 0) {
#pragma unroll
                for (int i = 0; i < 8; ++i) b[i] = (bf16)avec[kk * 32 + lg * 8 + i];
            }
            dacc = __builtin_amdgcn_mfma_f32_16x16x32_bf16(a, b, dacc, 0, 0, 0);
        }
        if (lr == 0) {
#pragma unroll
            for (int r = 0; r < 4; ++r) part_l[wv * 16 + lg * 4 + r] = dacc[r];
        }
    }
    __syncthreads();

    // ---- phase 4b: per-edge output ----
    float part = part_l[el];

    if (MODE == 0) {
        float att = fsigmoid(part + abias[0]);
        float scale = att * em;
        f32x2 sc2 = {scale, scale};
        uchar* edst = efout + (size_t)(ebase + el) * 128 + q * 32;
#pragma unroll
        for (int cpair = 0; cpair < 2; ++cpair) {
            uint4 wout;
#pragma unroll
            for (int cc = 0; cc < 2; ++cc) {
                int c = cpair * 2 + cc;
                int sl = (q * 4 + c) ^ (el & 7);
                uint4 mu = __builtin_bit_cast(uint4, *(const bf16x8*)(T + el * 128 + sl * 8));
                uint w0 = 0, w1 = 0;
                {
                    uint m0 = (&mu.x)[0], m1 = (&mu.x)[1];
                    f32x2 a2 = f32x2{__uint_as_float(m0 << 16), __uint_as_float(m0 & 0xffff0000u)} * sc2;
                    f32x2 b2v = f32x2{__uint_as_float(m1 << 16), __uint_as_float(m1 & 0xffff0000u)} * sc2;
                    w0 = __builtin_amdgcn_cvt_pk_fp8_f32(a2.x, a2.y, w0, false);
                    w0 = __builtin_amdgcn_cvt_pk_fp8_f32(b2v.x, b2v.y, w0, true);
                }
                {
                    uint m2 = (&mu.x)[2], m3 = (&mu.x)[3];
                    f32x2 a2 = f32x2{__uint_as_float(m2 << 16), __uint_as_float(m2 & 0xffff0000u)} * sc2;
                    f32x2 b2v = f32x2{__uint_as_float(m3 << 16), __uint_as_float(m3 & 0xffff0000u)} * sc2;
                    w1 = __builtin_amdgcn_cvt_pk_fp8_f32(a2.x, a2.y, w1, false);
                    w1 = __builtin_amdgcn_cvt_pk_fp8_f32(b2v.x, b2v.y, w1, true);
                }
                (&wout.x)[cc * 2 + 0] = w0;
                (&wout.x)[cc * 2 + 1] = w1;
            }
            *(uint4*)(edst + cpair * 16) = wout;
        }
    } else {
        if (q == 0) {
            float inv = 1.f / (sqrtf(radial + 1e-8f) + 1.f);
            float s = part * em * inv;
            int sI = ebase + el;
            trans[sI * 3 + 0] = dx * s;
            trans[sI * 3 + 1] = dy * s;
            trans[sI * 3 + 2] = dz * s;
        }
    }
}

// ---------------- node MLP kernel ----------------
__global__ __launch_bounds__(256, 2) void node_kernel(
    float* __restrict__ h_cur, const bf16* __restrict__ agg_bf,
    const bf16* __restrict__ w1t, const float* __restrict__ b1,
    const bf16* __restrict__ w2t, const float* __restrict__ b2,
    const float* __restrict__ nmask) {
    constexpr int SRN = 264;
    constexpr int TRN = 136;
    __shared__ __align__(16) bf16 ninp[64 * SRN];
    __shared__ __align__(16) bf16 t1[64 * TRN];

    int t = threadIdx.x, lane = t & 63, wv = t >> 6;
    int lr = lane & 15, lg = lane >> 4;
    int nbase = blockIdx.x * 64;

    {   // stage ninp = [bf16(h), agg_bf]
        int nl = t >> 2, q = t & 3;
        int node = nbase + nl;
        bf16* dst = ninp + nl * SRN;
        if (node < N_NODES) {
            const float4* hr = (const float4*)(h_cur + (size_t)node * H);
            const bf16* ar = agg_bf + (size_t)node * H;
#pragma unroll
            for (int pp = 0; pp < 8; ++pp) {
                int ch = pp * 4 + q;
                float4 v = hr[ch];
                dst[ch * 4 + 0] = (bf16)v.x; dst[ch * 4 + 1] = (bf16)v.y;
                dst[ch * 4 + 2] = (bf16)v.z; dst[ch * 4 + 3] = (bf16)v.w;
            }
#pragma unroll
            for (int pp = 0; pp < 4; ++pp) {
                int ch = pp * 4 + q;
                *(bf16x8*)(dst + 128 + ch * 8) = *(const bf16x8*)(ar + ch * 8);
            }
        } else {
#pragma unroll
            for (int pp = 0; pp < 8; ++pp) {
                int ch = pp * 4 + q;
#pragma unroll
                for (int k = 0; k < 4; ++k) {
                    dst[ch * 4 + k] = (bf16)0.f;
                    dst[128 + ch * 4 + k] = (bf16)0.f;
                }
            }
        }
    }
    __syncthreads();

    f32x4 acc[4][2];
#pragma unroll
    for (int er = 0; er < 4; ++er)
#pragma unroll
        for (int j = 0; j < 2; ++j) acc[er][j] = (f32x4)0.f;
    wave_gemm<8, SRN, 256>(ninp, w1t, acc, lr, lg, wv);
    epi_silu_store(acc, b1, t1, TRN, lr, lg, wv);
    __syncthreads();

    f32x4 acc2[4][2];
#pragma unroll
    for (int er = 0; er < 4; ++er)
#pragma unroll
        for (int j = 0; j < 2; ++j) acc2[er][j] = (f32x4)0.f;
    wave_gemm<4, TRN, 128>(t1, w2t, acc2, lr, lg, wv);

    float bb0 = b2[(wv * 2 + 0) * 16 + lr];
    float bb1 = b2[(wv * 2 + 1) * 16 + lr];
#pragma unroll
    for (int er = 0; er < 4; ++er) {
#pragma unroll
        for (int j = 0; j < 2; ++j) {
            float bb = j ? bb1 : bb0;
            int feat = (wv * 2 + j) * 16 + lr;
#pragma unroll
            for (int r = 0; r < 4; ++r) {
                int node = nbase + er * 16 + lg * 4 + r;
                if (node < N_NODES) {
                    size_t idx = (size_t)node * H + feat;
                    float nm = nmask[node];
                    h_cur[idx] = (h_cur[idx] + acc2[er][j][r] + bb) * nm;  // fp32 residual
                }
            }
        }
    }
}

// ---------------- launch ----------------
extern "C" void kernel_launch(void* const* d_in, const int* in_sizes, int n_in,
                              void* d_out, int out_size, void* d_ws, size_t ws_size,
                              hipStream_t stream) {
    (void)in_sizes; (void)n_in; (void)out_size; (void)ws_size;
    const float* h_in  = (const float*)d_in[0];
    const float* x_in  = (const float*)d_in[1];
    const int*   ei    = (const int*)d_in[2];
    const float* eattr = (const float*)d_in[3];
    const float* nmask = (const float*)d_in[4];
    const float* emask = (const float*)d_in[5];
    const float* e_w1  = (const float*)d_in[6];
    const float* e_b1  = (const float*)d_in[7];
    const float* e_w2  = (const float*)d_in[8];
    const float* e_b2  = (const float*)d_in[9];
    const float* a_w   = (const float*)d_in[10];
    const float* a_b   = (const float*)d_in[11];
    const float* n_w1  = (const float*)d_in[12];
    const float* n_b1  = (const float*)d_in[13];
    const float* n_w2  = (const float*)d_in[14];
    const float* n_b2  = (const float*)d_in[15];
    const float* c_w1  = (const float*)d_in[16];
    const float* c_b1  = (const float*)d_in[17];
    const float* c_w2  = (const float*)d_in[18];
    const float* c_b2  = (const float*)d_in[19];
    const float* c_w3  = (const float*)d_in[20];
    float* out = (float*)d_out;

    char* p = (char*)d_ws;
    auto alloc = [&](size_t bytes) { char* r = p; p += (bytes + 255) & ~(size_t)255; return r; };
    float* h_cur  = (float*)alloc((size_t)N_NODES * H * 4);     // 25.6 MB
    bf16*  Pb     = (bf16*) alloc((size_t)N_NODES * H * 2);     // 12.8 MB
    bf16*  Qb     = (bf16*) alloc((size_t)N_NODES * H * 2);     // 12.8 MB (agg aliases Q)
    bf16*  agg_bf = Qb;
    uchar* ef     = (uchar*)alloc((size_t)N_EDGES * 128);       // 102.4 MB fp8, slot-indexed
    float* trans  = (float*)ef;                                 // alias: ef dead before edge<1>
    int*   deg    = (int*)  alloc((size_t)N_NODES * 4);
    int*   off    = (int*)  alloc((size_t)N_NODES * 4);
    int*   bsum   = (int*)  alloc((size_t)NB_SCAN * 4);
    uint*  rc_pm  = (uint*) alloc((size_t)N_EDGES * 4);         // slot-ordered row<<16|col
    bf16*  eaem_pm= (bf16*) alloc((size_t)N_EDGES * 2 * 2);     // slot-ordered {eattr, emask}
    bf16*  e_w1t  = (bf16*) alloc((size_t)2 * 128 * 256 * 2);
    bf16*  e_w2t  = (bf16*) alloc((size_t)2 * 128 * 128 * 2);
    bf16*  n_w1t  = (bf16*) alloc((size_t)2 * 128 * 256 * 2);
    bf16*  n_w2t  = (bf16*) alloc((size_t)2 * 128 * 128 * 2);
    bf16*  c_w1t  = (bf16*) alloc((size_t)128 * 256 * 2);
    bf16*  c_w2t  = (bf16*) alloc((size_t)128 * 128 * 2);
    // total ~161 MB

    auto tp = [&](bf16* dst, const float* src, int K, int KP) {
        int tot = 128 * KP;
        transpose_pad_kernel<<<(tot + 255) / 256, 256, 0, stream>>>(dst, src, K, 128, KP);
    };
    tp(e_w1t, e_w1, 258, 256);               tp(e_w1t + 128 * 256, e_w1 + 258 * 128, 258, 256);
    tp(e_w2t, e_w2, 128, 128);               tp(e_w2t + 128 * 128, e_w2 + 128 * 128, 128, 128);
    tp(n_w1t, n_w1, 256, 256);               tp(n_w1t + 128 * 256, n_w1 + 256 * 128, 256, 256);
    tp(n_w2t, n_w2, 128, 128);               tp(n_w2t + 128 * 128, n_w2 + 128 * 128, 128, 128);
    tp(c_w1t, c_w1, 258, 256);
    tp(c_w2t, c_w2, 128, 128);

    h_init_kernel<<<(N_NODES * H + 255) / 256, 256, 0, stream>>>(h_in, h_cur, N_NODES * H);

    // ---- CSR build + slot-ordered packed metadata ----
    hipMemsetAsync(deg, 0, (size_t)N_NODES * 4, stream);
    count_kernel<<<(N_EDGES + 255) / 256, 256, 0, stream>>>(ei, deg);
    scan1_kernel<<<NB_SCAN, 256, 0, stream>>>(deg, off, bsum);
    scan2_kernel<<<1, 256, 0, stream>>>(bsum);
    scan3_kernel<<<NB_SCAN, 256, 0, stream>>>(off, bsum);
    fill2_kernel<<<(N_EDGES + 255) / 256, 256, 0, stream>>>(
        ei, eattr, emask, off, rc_pm, eaem_pm);

    int ngrid = (N_NODES + 3) / 4;
    int pqgrid = (N_NODES + 63) / 64;
    for (int i = 0; i < 2; ++i) {
        pq_kernel<<<pqgrid, 256, 0, stream>>>(
            h_cur, e_w1t + (size_t)i * 128 * 256, e_b1 + i * H, Pb, Qb);
        edge_kernel<0><<<N_EDGES / 64, 256, 0, stream>>>(
            Pb, Qb, rc_pm, eaem_pm, x_in,
            e_w1 + (size_t)i * 258 * 128 + 256 * 128,   // w_r
            e_w1 + (size_t)i * 258 * 128 + 257 * 128,   // w_e
            e_w2t + (size_t)i * 128 * 128, e_b2 + i * H,
            a_w + i * H, a_b + i, ef, nullptr);
        gather_h_kernel<<<ngrid, 256, 0, stream>>>(ef, off, agg_bf);  // into Qb (dead)
        node_kernel<<<(N_NODES + 63) / 64, 256, 0, stream>>>(
            h_cur, agg_bf,
            n_w1t + (size_t)i * 128 * 256, n_b1 + i * H,
            n_w2t + (size_t)i * 128 * 128, n_b2 + i * H, nmask);
    }
    // coord path
    pq_kernel<<<pqgrid, 256, 0, stream>>>(h_cur, c_w1t, c_b1, Pb, Qb);
    edge_kernel<1><<<N_EDGES / 64, 256, 0, stream>>>(
        Pb, Qb, rc_pm, eaem_pm, x_in,
        c_w1 + 256 * 128, c_w1 + 257 * 128,
        c_w2t, c_b2, c_w3, nullptr, nullptr, trans);
    gather_x_kernel<<<ngrid, 256, 0, stream>>>(trans, off, x_in, nmask,
                                               out + (size_t)N_NODES * H);

    out_h_kernel<<<(N_NODES * H + 255) / 256, 256, 0, stream>>>(h_cur, nmask, out);
}